// Round 6
// baseline (387.374 us; speedup 1.0000x reference)
//
#include <hip/hip_runtime.h>
#include <math.h>

#define N_POS 8000
#define C_CH  128
#define KSPLIT 5
#define KT_PER 25      // 125 k-tiles of 64 keys, 25 per split

typedef __bf16 bf16x8 __attribute__((ext_vector_type(8)));
typedef float  f32x4  __attribute__((ext_vector_type(4)));

#define MFMA(a,b,c) __builtin_amdgcn_mfma_f32_16x16x32_bf16((a),(b),(c),0,0,0)

// MFMA 16x16x32 lane layouts (verified m89/m120):
//   A[m][k]: m = lane&15, k = (lane>>4)*8 + j   (lane's 8 elems contiguous in k)
//   B[k][n]: n = lane&15, k = (lane>>4)*8 + j
//   D[m][n]: n = lane&15, m = (lane>>4)*4 + reg

// ---------------------------------------------------------------------------
// Kernel A: QKV projections via MFMA. grid 500 (n-tiles of 16), block 256.
// Also zero-inits BN stat accumulators (block 0) so no memset dispatch needed.
// q_bf,k_bf: [n][16] bf16.  v_bf: [c][8000] bf16.
// ---------------------------------------------------------------------------
__global__ __launch_bounds__(256) void qkv_kernel(
    const float* __restrict__ x,
    const float* __restrict__ wq, const float* __restrict__ bq,
    const float* __restrict__ wk, const float* __restrict__ bk,
    const float* __restrict__ wv, const float* __restrict__ bv,
    __bf16* __restrict__ q_bf, __bf16* __restrict__ k_bf, __bf16* __restrict__ v_bf,
    float* __restrict__ bn_stats)
{
    __shared__ __bf16 x_lds[2048];   // 256 chunks: (coct*16 + n)*8 elems, 4 KB
    __shared__ __bf16 v_out[2048];   // [vch][16n], 4 KB

    const int t    = threadIdx.x;
    const int n0   = blockIdx.x * 16;
    const int lane = t & 63;
    const int w    = t >> 6;
    const int l15  = lane & 15;
    const int quad = lane >> 4;

    if (blockIdx.x == 0 && t < 256) bn_stats[t] = 0.f;   // bn_sum[128]+bn_sumsq[128]

    // stage x tile [128c x 16n] fp32 -> bf16 B-fragment chunks
    for (int r = 0; r < 2; ++r) {
        int f = r * 256 + t;
        int ch = f >> 2, n4 = f & 3;
        float4 xv = *reinterpret_cast<const float4*>(&x[ch * N_POS + n0 + n4 * 4]);
        int coct = ch >> 3, cl = ch & 7;
        x_lds[((coct * 16 + n4 * 4 + 0) * 8) + cl] = (__bf16)xv.x;
        x_lds[((coct * 16 + n4 * 4 + 1) * 8) + cl] = (__bf16)xv.y;
        x_lds[((coct * 16 + n4 * 4 + 2) * 8) + cl] = (__bf16)xv.z;
        x_lds[((coct * 16 + n4 * 4 + 3) * 8) + cl] = (__bf16)xv.w;
    }

    // A-frags: weight rows fp32->bf16 in regs. wave w owns mtiles {w, 4+w, 8+w<10}
    bf16x8 aw[3][4];
    f32x4  acc[3];
    const int nmt = (w < 2) ? 3 : 2;
    for (int mi = 0; mi < nmt; ++mi) {
        int mt = w + 4 * mi;
        const float *wrow, *brow;
        if (mt == 0)      { wrow = wq + l15 * 128;               brow = bq; }
        else if (mt == 1) { wrow = wk + l15 * 128;               brow = bk; }
        else              { wrow = wv + ((mt - 2) * 16 + l15) * 128;
                            brow = bv + (mt - 2) * 16; }
        for (int ks = 0; ks < 4; ++ks) {
            float4 f0 = *reinterpret_cast<const float4*>(wrow + ks * 32 + quad * 8);
            float4 f1 = *reinterpret_cast<const float4*>(wrow + ks * 32 + quad * 8 + 4);
            bf16x8 a;
            a[0]=(__bf16)f0.x; a[1]=(__bf16)f0.y; a[2]=(__bf16)f0.z; a[3]=(__bf16)f0.w;
            a[4]=(__bf16)f1.x; a[5]=(__bf16)f1.y; a[6]=(__bf16)f1.z; a[7]=(__bf16)f1.w;
            aw[mi][ks] = a;
        }
        acc[mi][0] = brow[quad * 4 + 0]; acc[mi][1] = brow[quad * 4 + 1];
        acc[mi][2] = brow[quad * 4 + 2]; acc[mi][3] = brow[quad * 4 + 3];
    }
    __syncthreads();

    for (int ks = 0; ks < 4; ++ks) {
        bf16x8 b = *reinterpret_cast<const bf16x8*>(
            &x_lds[((ks * 4 + quad) * 16 + l15) * 8]);
        for (int mi = 0; mi < nmt; ++mi)
            acc[mi] = MFMA(aw[mi][ks], b, acc[mi]);
    }

    union S4 { short4 s; __bf16 b[4]; };
    for (int mi = 0; mi < nmt; ++mi) {
        int mt = w + 4 * mi;
        S4 u;
        u.b[0]=(__bf16)acc[mi][0]; u.b[1]=(__bf16)acc[mi][1];
        u.b[2]=(__bf16)acc[mi][2]; u.b[3]=(__bf16)acc[mi][3];
        int n = n0 + l15;
        if (mt == 0) {
            *reinterpret_cast<short4*>(&q_bf[n * 16 + quad * 4]) = u.s;
        } else if (mt == 1) {
            *reinterpret_cast<short4*>(&k_bf[n * 16 + quad * 4]) = u.s;
        } else {
            int ch0 = (mt - 2) * 16 + quad * 4;
            v_out[(ch0 + 0) * 16 + l15] = u.b[0];
            v_out[(ch0 + 1) * 16 + l15] = u.b[1];
            v_out[(ch0 + 2) * 16 + l15] = u.b[2];
            v_out[(ch0 + 3) * 16 + l15] = u.b[3];
        }
    }
    __syncthreads();
    // coalesced v store: 128 ch x 16 n (one int4 per thread)
    {
        int ch = t >> 1, half = t & 1;
        int4 d = *reinterpret_cast<const int4*>(&v_out[ch * 16 + half * 8]);
        *reinterpret_cast<int4*>(&v_bf[ch * N_POS + n0 + half * 8]) = d;
    }
}

// ---------------------------------------------------------------------------
// Kernel B: fused attention, split-K, MFMA. Q-tile 64, K-tile 64.
// V and K fragments loaded GLOBAL->VGPR directly (A-layout is contiguous in
// memory; v_bf/k_bf are L2-hot). Only P (64q x 64k bf16, 8 KB) goes through
// LDS, fragment-packed so all reads are contiguous-1KB conflict-free.
// Plain VGPR loads are not drained at s_barrier -> next-tile prefetch issued
// before PV survives both barriers; first use is next iter's S phase.
// grid 625 (qt = b%125 -> 64 queries, sp = b/125 -> 25 k-tiles of 64).
// ---------------------------------------------------------------------------
__global__ __launch_bounds__(256, 3) void attn_kernel(
    const __bf16* __restrict__ q_bf, const __bf16* __restrict__ k_bf,
    const __bf16* __restrict__ v_bf, __bf16* __restrict__ av_part,
    float* __restrict__ l_part)
{
    __shared__ __bf16 p_lds[4096];   // 8 KB: chunk((qh*8+oct)*16 + q15)

    const int t    = threadIdx.x;
    const int qt   = blockIdx.x % 125;
    const int sp   = blockIdx.x / 125;
    const int n0q  = qt * 64;
    const int lane = t & 63;
    const int w    = t >> 6;
    const int l15  = lane & 15;
    const int quad = lane >> 4;

    // Q B-frags (k-dim 16 padded to 32 with zeros in quads 2,3)
    bf16x8 aq[4];
    for (int qh = 0; qh < 4; ++qh) {
        for (int j = 0; j < 8; ++j) aq[qh][j] = (__bf16)0.0f;
        if (quad < 2)
            aq[qh] = *reinterpret_cast<const bf16x8*>(
                &q_bf[(n0q + qh * 16 + l15) * 16 + quad * 8]);
    }
    bf16x8 ones;
    for (int j = 0; j < 8; ++j) ones[j] = (__bf16)1.0f;

    f32x4 acc[2][4];
    for (int mi = 0; mi < 2; ++mi)
        for (int qh = 0; qh < 4; ++qh)
            for (int r = 0; r < 4; ++r) acc[mi][qh][r] = 0.f;
    f32x4 lacc;
    for (int r = 0; r < 4; ++r) lacc[r] = 0.f;

    const int kt0 = sp * KT_PER;
    const __bf16* vp0 = v_bf + (size_t)((2 * w)     * 16 + l15) * N_POS + kt0 * 64 + quad * 8;
    const __bf16* vp1 = v_bf + (size_t)((2 * w + 1) * 16 + l15) * N_POS + kt0 * 64 + quad * 8;
    const __bf16* kp  = k_bf + (size_t)(kt0 * 64 + w * 16 + l15) * 16 + quad * 8;

    // preload tile kt0 fragments into registers
    bf16x8 ak, a0[2], a1[2];
    for (int j = 0; j < 8; ++j) ak[j] = (__bf16)0.0f;
    if (quad < 2) ak = *reinterpret_cast<const bf16x8*>(kp);
    for (int ks = 0; ks < 2; ++ks) {
        a0[ks] = *reinterpret_cast<const bf16x8*>(vp0 + ks * 32);
        a1[ks] = *reinterpret_cast<const bf16x8*>(vp1 + ks * 32);
    }

    const int pwc = (w * 2 + (quad >> 1)) * 16 + l15;   // P-write chunk (per qh-group)
    const int pwo = (quad & 1) * 4;                     // P-write elem offset

    for (int kt = kt0; kt < kt0 + KT_PER; ++kt) {
        // ---- S phase: wave w owns keys w*16..+15 (A = K rows, B = Q regs)
        union S4 { short4 sh; __bf16 b[4]; };
#pragma unroll
        for (int qh = 0; qh < 4; ++qh) {
            f32x4 s;
            for (int r = 0; r < 4; ++r) s[r] = 0.f;
            s = MFMA(ak, aq[qh], s);          // D[m=key][n=q]
            S4 u;
            u.b[0] = (__bf16)__expf(s[0]); u.b[1] = (__bf16)__expf(s[1]);
            u.b[2] = (__bf16)__expf(s[2]); u.b[3] = (__bf16)__expf(s[3]);
            *reinterpret_cast<short4*>(&p_lds[(qh * 128 + pwc) * 8 + pwo]) = u.sh;
        }
        __syncthreads();   // P visible (pure exec sync; no LDS-DMA to drain)

        // ---- prefetch next tile's V/K fragments (VGPR loads; waitcnt lands
        //      at first use = next iter's S/PV, hidden under this iter's PV)
        bf16x8 akN = ak, a0N[2], a1N[2];
        a0N[0] = a0[0]; a0N[1] = a0[1]; a1N[0] = a1[0]; a1N[1] = a1[1];
        if (kt + 1 < kt0 + KT_PER) {
            if (quad < 2) akN = *reinterpret_cast<const bf16x8*>(kp + 64 * 16);
            for (int ks = 0; ks < 2; ++ks) {
                a0N[ks] = *reinterpret_cast<const bf16x8*>(vp0 + 64 + ks * 32);
                a1N[ks] = *reinterpret_cast<const bf16x8*>(vp1 + 64 + ks * 32);
            }
        }

        // ---- PV phase: wave w owns ch-tiles {2w, 2w+1}; P reads contiguous
#pragma unroll
        for (int ks = 0; ks < 2; ++ks) {
            bf16x8 p[4];
#pragma unroll
            for (int qh = 0; qh < 4; ++qh)
                p[qh] = *reinterpret_cast<const bf16x8*>(
                    &p_lds[((qh * 8 + ks * 4 + quad) * 16 + l15) * 8]);
#pragma unroll
            for (int qh = 0; qh < 4; ++qh) {
                acc[0][qh] = MFMA(a0[ks], p[qh], acc[0][qh]);
                acc[1][qh] = MFMA(a1[ks], p[qh], acc[1][qh]);
            }
            lacc = MFMA(ones, p[w], lacc);   // row-sum for this wave's q-group
        }
        __syncthreads();   // P reads done before next iter's writes

        ak = akN; a0[0] = a0N[0]; a0[1] = a0N[1]; a1[0] = a1N[0]; a1[1] = a1N[1];
        kp += 64 * 16; vp0 += 64; vp1 += 64;
    }

    // write av partials (bf16) : av_part[sp][n][c]
    __bf16* dst = av_part + (size_t)sp * 1024000;
    union S4o { short4 sh; __bf16 b[4]; };
    for (int mi = 0; mi < 2; ++mi)
        for (int qh = 0; qh < 4; ++qh) {
            S4o o;
            o.b[0] = (__bf16)acc[mi][qh][0]; o.b[1] = (__bf16)acc[mi][qh][1];
            o.b[2] = (__bf16)acc[mi][qh][2]; o.b[3] = (__bf16)acc[mi][qh][3];
            *reinterpret_cast<short4*>(
                &dst[(size_t)(n0q + qh * 16 + l15) * 128 + (2 * w + mi) * 16 + quad * 4]) = o.sh;
        }
    if (quad == 0)
        l_part[sp * N_POS + n0q + w * 16 + l15] = lacc[0];
}

// ---------------------------------------------------------------------------
// Kernel C: split-K reduce + normalize (fp32) fused with y = wa@av + ba (MFMA)
// + BN stats. grid 500 (n-tiles of 16), block 256.
// ---------------------------------------------------------------------------
__global__ __launch_bounds__(256) void proj_out_kernel(
    const __bf16* __restrict__ av_part, const float* __restrict__ l_part,
    const float* __restrict__ wa, const float* __restrict__ ba,
    float* __restrict__ y_ws, float* __restrict__ bn_sum, float* __restrict__ bn_sumsq)
{
    __shared__ __bf16 b_lds[2048];   // 16n x 128c fragment-packed, 4 KB

    const int t    = threadIdx.x;
    const int n0   = blockIdx.x * 16;
    const int lane = t & 63;
    const int w    = t >> 6;
    const int l15  = lane & 15;
    const int quad = lane >> 4;

    // build normalized B tile: 256 c-octets, 1 per thread (coalesced reads)
    {
        int n = t >> 4, oc = t & 15;
        float l = 0.f;
#pragma unroll
        for (int s = 0; s < KSPLIT; ++s) l += l_part[s * N_POS + n0 + n];
        float sum[8];
#pragma unroll
        for (int i = 0; i < 8; ++i) sum[i] = 0.f;
#pragma unroll
        for (int s = 0; s < KSPLIT; ++s) {
            bf16x8 p = *reinterpret_cast<const bf16x8*>(
                &av_part[(size_t)s * 1024000 + (size_t)(n0 + n) * 128 + oc * 8]);
#pragma unroll
            for (int i = 0; i < 8; ++i) sum[i] += (float)p[i];
        }
        float inv = 1.f / l;
        union { int4 iv; __bf16 b[8]; } u;
#pragma unroll
        for (int i = 0; i < 8; ++i) u.b[i] = (__bf16)(sum[i] * inv);
        *reinterpret_cast<int4*>(&b_lds[(oc * 16 + n) * 8]) = u.iv;
    }

    // A-frags: wa rows for mtiles {2w, 2w+1}
    bf16x8 aw[2][4];
    f32x4  acc[2];
    for (int mi = 0; mi < 2; ++mi) {
        int mt = 2 * w + mi;
        const float* wrow = wa + (mt * 16 + l15) * 128;
        for (int ks = 0; ks < 4; ++ks) {
            float4 f0 = *reinterpret_cast<const float4*>(wrow + ks * 32 + quad * 8);
            float4 f1 = *reinterpret_cast<const float4*>(wrow + ks * 32 + quad * 8 + 4);
            bf16x8 a;
            a[0]=(__bf16)f0.x; a[1]=(__bf16)f0.y; a[2]=(__bf16)f0.z; a[3]=(__bf16)f0.w;
            a[4]=(__bf16)f1.x; a[5]=(__bf16)f1.y; a[6]=(__bf16)f1.z; a[7]=(__bf16)f1.w;
            aw[mi][ks] = a;
        }
        acc[mi][0] = ba[mt * 16 + quad * 4 + 0];
        acc[mi][1] = ba[mt * 16 + quad * 4 + 1];
        acc[mi][2] = ba[mt * 16 + quad * 4 + 2];
        acc[mi][3] = ba[mt * 16 + quad * 4 + 3];
    }
    __syncthreads();

    for (int ks = 0; ks < 4; ++ks) {
        bf16x8 b = *reinterpret_cast<const bf16x8*>(
            &b_lds[((ks * 4 + quad) * 16 + l15) * 8]);
        for (int mi = 0; mi < 2; ++mi)
            acc[mi] = MFMA(aw[mi][ks], b, acc[mi]);
    }

    // y writes [c][n] + BN partial stats (one add per channel per block)
    for (int mi = 0; mi < 2; ++mi) {
#pragma unroll
        for (int r = 0; r < 4; ++r) {
            int ch = (2 * w + mi) * 16 + quad * 4 + r;
            float v = acc[mi][r];
            y_ws[ch * N_POS + n0 + l15] = v;
            float s1 = v, s2 = v * v;
#pragma unroll
            for (int off = 8; off >= 1; off >>= 1) {
                s1 += __shfl_xor(s1, off, 64);
                s2 += __shfl_xor(s2, off, 64);
            }
            if (l15 == 0) {
                atomicAdd(&bn_sum[ch],   s1);
                atomicAdd(&bn_sumsq[ch], s2);
            }
        }
    }
}

// ---------------------------------------------------------------------------
// Kernel D: BatchNorm (training stats) + ReLU + residual. grid 1000, block 256.
// ---------------------------------------------------------------------------
__global__ __launch_bounds__(256) void bn_relu_kernel(
    const float* __restrict__ y_ws, const float* __restrict__ x,
    const float* __restrict__ bn_sum, const float* __restrict__ bn_sumsq,
    const float* __restrict__ bn_w, const float* __restrict__ bn_b,
    float* __restrict__ out)
{
    const int i4 = blockIdx.x * 256 + threadIdx.x;
    const int c  = i4 / 2000;
    const float mean  = bn_sum[c]   * (1.f / 8000.f);
    const float var   = bn_sumsq[c] * (1.f / 8000.f) - mean * mean;
    const float rstd  = rsqrtf(var + 1e-5f);
    const float scale = bn_w[c] * rstd;
    const float shift = bn_b[c] - mean * scale;

    float4 y4 = reinterpret_cast<const float4*>(y_ws)[i4];
    float4 x4 = reinterpret_cast<const float4*>(x)[i4];
    float4 o4;
    o4.x = fmaxf(y4.x * scale + shift, 0.f) + x4.x;
    o4.y = fmaxf(y4.y * scale + shift, 0.f) + x4.y;
    o4.z = fmaxf(y4.z * scale + shift, 0.f) + x4.z;
    o4.w = fmaxf(y4.w * scale + shift, 0.f) + x4.w;
    reinterpret_cast<float4*>(out)[i4] = o4;
}

// ---------------------------------------------------------------------------
extern "C" void kernel_launch(void* const* d_in, const int* in_sizes, int n_in,
                              void* d_out, int out_size, void* d_ws, size_t ws_size,
                              hipStream_t stream)
{
    const float* x    = (const float*)d_in[0];
    const float* wq   = (const float*)d_in[1];
    const float* bq   = (const float*)d_in[2];
    const float* wk   = (const float*)d_in[3];
    const float* bk   = (const float*)d_in[4];
    const float* wv   = (const float*)d_in[5];
    const float* bv   = (const float*)d_in[6];
    const float* wa   = (const float*)d_in[7];
    const float* ba   = (const float*)d_in[8];
    const float* bn_w = (const float*)d_in[9];
    const float* bn_b = (const float*)d_in[10];
    float* out = (float*)d_out;

    char* base = (char*)d_ws;
    // byte layout (~17.1 MB):
    __bf16* av_part = (__bf16*)base;                   // 10,240,000 B (5 x 8000 x 128 bf16)
    __bf16* q_bf    = (__bf16*)(base + 10240000);      //    256,000 B
    __bf16* k_bf    = (__bf16*)(base + 10496000);      //    256,000 B
    __bf16* v_bf    = (__bf16*)(base + 10752000);      //  2,048,000 B
    float*  l_part  = (float*)(base + 12800000);       //    160,000 B
    float*  bn_sum   = (float*)(base + 12960000);      //        512 B
    float*  bn_sumsq = bn_sum + 128;                   //        512 B
    float*  y_ws    = (float*)(base + 12961024);       //  4,096,000 B

    qkv_kernel<<<500, 256, 0, stream>>>(x, wq, bq, wk, bk, wv, bv,
                                        q_bf, k_bf, v_bf, bn_sum);
    attn_kernel<<<125 * KSPLIT, 256, 0, stream>>>(q_bf, k_bf, v_bf, av_part, l_part);
    proj_out_kernel<<<500, 256, 0, stream>>>(av_part, l_part, wa, ba, y_ws, bn_sum, bn_sumsq);
    bn_relu_kernel<<<1000, 256, 0, stream>>>(y_ws, x, bn_sum, bn_sumsq, bn_w, bn_b, out);
}

// Round 7
// 337.599 us; speedup vs baseline: 1.1474x; 1.1474x over previous
//
#include <hip/hip_runtime.h>
#include <math.h>

#define N_POS 8000

typedef __bf16 bf16x8 __attribute__((ext_vector_type(8)));
typedef float  f32x4  __attribute__((ext_vector_type(4)));

#define MFMA(a,b,c) __builtin_amdgcn_mfma_f32_16x16x32_bf16((a),(b),(c),0,0,0)

// MFMA 16x16x32 lane layouts (verified m89/m120):
//   A[m][k]: m = lane&15, k = (lane>>4)*8 + j   (lane's 8 elems contiguous in k)
//   B[k][n]: n = lane&15, k = (lane>>4)*8 + j
//   D[m][n]: n = lane&15, m = (lane>>4)*4 + reg

// ---------------------------------------------------------------------------
// Kernel A: QKV projections via MFMA. grid 250 (n-tiles of 32), block 256.
// q_bf,k_bf: [n][16] bf16 (fragment-contiguous for attn's A/B loads).
// v_pk: FRAGMENT-PACKED tiles: chunk((kt*16 + ct*2 + ks)*4 + quad)*16 + l15,
// 16B chunks, so attn V-fragment loads are 1KB-contiguous per wave.
// Block 0 also zeroes the BN stat accumulators.
// ---------------------------------------------------------------------------
__global__ __launch_bounds__(256) void qkv_kernel(
    const float* __restrict__ x,
    const float* __restrict__ wq, const float* __restrict__ bq,
    const float* __restrict__ wk, const float* __restrict__ bk,
    const float* __restrict__ wv, const float* __restrict__ bv,
    __bf16* __restrict__ q_bf, __bf16* __restrict__ k_bf, __bf16* __restrict__ v_pk,
    float* __restrict__ bn_stats)
{
    __shared__ __bf16 x_lds[32 * 136];          // [n][c]
    __shared__ __bf16 v_out[128 * 40];          // [ch][n-local], stride 40 (16B-aligned rows)

    const int t    = threadIdx.x;
    const int n0   = blockIdx.x * 32;
    const int lane = t & 63;
    const int w    = t >> 6;
    const int l15  = lane & 15;
    const int quad = lane >> 4;

    if (blockIdx.x == 0) bn_stats[t] = 0.f;   // bn_sum[128] + bn_sumsq[128]

    // stage x tile [128c x 32n] fp32 -> x_lds[n][c] bf16 (transpose+convert)
    for (int r = 0; r < 4; ++r) {
        int f = r * 256 + t;
        int ch = f >> 3, n4 = f & 7;
        float4 xv = *reinterpret_cast<const float4*>(&x[ch * N_POS + n0 + n4 * 4]);
        x_lds[(n4 * 4 + 0) * 136 + ch] = (__bf16)xv.x;
        x_lds[(n4 * 4 + 1) * 136 + ch] = (__bf16)xv.y;
        x_lds[(n4 * 4 + 2) * 136 + ch] = (__bf16)xv.z;
        x_lds[(n4 * 4 + 3) * 136 + ch] = (__bf16)xv.w;
    }

    // A-frags: weight rows fp32->bf16 in regs. wave w owns mtiles {w, w+4, w+8<10}
    bf16x8 aw[3][4];
    f32x4  acc[3][2];
    const int nmt = (w < 2) ? 3 : 2;
    for (int mi = 0; mi < nmt; ++mi) {
        int mt = w + 4 * mi;
        const float *wrow, *brow;
        if (mt == 0)      { wrow = wq + l15 * 128;               brow = bq; }
        else if (mt == 1) { wrow = wk + l15 * 128;               brow = bk; }
        else              { wrow = wv + ((mt - 2) * 16 + l15) * 128;
                            brow = bv + (mt - 2) * 16; }
        for (int ks = 0; ks < 4; ++ks) {
            float4 f0 = *reinterpret_cast<const float4*>(wrow + ks * 32 + quad * 8);
            float4 f1 = *reinterpret_cast<const float4*>(wrow + ks * 32 + quad * 8 + 4);
            bf16x8 a;
            a[0]=(__bf16)f0.x; a[1]=(__bf16)f0.y; a[2]=(__bf16)f0.z; a[3]=(__bf16)f0.w;
            a[4]=(__bf16)f1.x; a[5]=(__bf16)f1.y; a[6]=(__bf16)f1.z; a[7]=(__bf16)f1.w;
            aw[mi][ks] = a;
        }
        for (int ni = 0; ni < 2; ++ni) {
            acc[mi][ni][0] = brow[quad * 4 + 0]; acc[mi][ni][1] = brow[quad * 4 + 1];
            acc[mi][ni][2] = brow[quad * 4 + 2]; acc[mi][ni][3] = brow[quad * 4 + 3];
        }
    }
    __syncthreads();

    for (int ks = 0; ks < 4; ++ks) {
        bf16x8 b0 = *reinterpret_cast<const bf16x8*>(&x_lds[(0  + l15) * 136 + ks * 32 + quad * 8]);
        bf16x8 b1 = *reinterpret_cast<const bf16x8*>(&x_lds[(16 + l15) * 136 + ks * 32 + quad * 8]);
        for (int mi = 0; mi < nmt; ++mi) {
            acc[mi][0] = MFMA(aw[mi][ks], b0, acc[mi][0]);
            acc[mi][1] = MFMA(aw[mi][ks], b1, acc[mi][1]);
        }
    }

    union S4 { short4 s; __bf16 b[4]; };
    for (int mi = 0; mi < nmt; ++mi) {
        int mt = w + 4 * mi;
        for (int ni = 0; ni < 2; ++ni) {
            S4 u;
            u.b[0]=(__bf16)acc[mi][ni][0]; u.b[1]=(__bf16)acc[mi][ni][1];
            u.b[2]=(__bf16)acc[mi][ni][2]; u.b[3]=(__bf16)acc[mi][ni][3];
            int n = n0 + ni * 16 + l15;
            if (mt == 0) {
                *reinterpret_cast<short4*>(&q_bf[n * 16 + quad * 4]) = u.s;
            } else if (mt == 1) {
                *reinterpret_cast<short4*>(&k_bf[n * 16 + quad * 4]) = u.s;
            } else {
                int ch0 = (mt - 2) * 16 + quad * 4;
                int nl  = ni * 16 + l15;
                v_out[(ch0 + 0) * 40 + nl] = u.b[0];
                v_out[(ch0 + 1) * 40 + nl] = u.b[1];
                v_out[(ch0 + 2) * 40 + nl] = u.b[2];
                v_out[(ch0 + 3) * 40 + nl] = u.b[3];
            }
        }
    }
    __syncthreads();

    // packed V store: this 32-n block is half (ksB) of key-tile kt = n0>>6
    const int kt  = n0 >> 6;
    const int ksB = (n0 >> 5) & 1;
    for (int r = 0; r < 2; ++r) {
        int c   = r * 256 + t;            // local chunk: ct*64 + qd*16 + p15
        int ct  = c >> 6, qd = (c >> 4) & 3, p15 = c & 15;
        int ch  = ct * 16 + p15;
        int4 d  = *reinterpret_cast<const int4*>(&v_out[ch * 40 + qd * 8]);
        int gch = (kt * 16 + ct * 2 + ksB) * 64 + qd * 16 + p15;
        *reinterpret_cast<int4*>(&v_pk[(size_t)gch * 8]) = d;   // 1KB-contig/wave
    }
}

// ---------------------------------------------------------------------------
// Kernel B: fused attention, split-K, MFMA. Q-tile 64, K-tile 64.
// V fragments loaded global->VGPR from fragment-packed v_pk (1KB contiguous
// per wave-instr). K A-frags from row-major k_bf (contiguous per half-wave).
// LDS: double-buffered P only (2x8KB) -> ONE barrier per k-tile.
// Epilogue transposes av through LDS for 1KB-contiguous global stores.
// grid 125*nsplit (qt = b%125 -> 64 queries, sp = b/125).
// ---------------------------------------------------------------------------
__global__ __launch_bounds__(256, 4) void attn_kernel(
    const __bf16* __restrict__ q_bf, const __bf16* __restrict__ k_bf,
    const __bf16* __restrict__ v_pk, __bf16* __restrict__ av_part,
    float* __restrict__ l_part, int nsplit)
{
    __shared__ __bf16 p_lds[2][4096];   // 16 KB total; reused for av epilogue

    const int t    = threadIdx.x;
    const int qt   = blockIdx.x % 125;
    const int sp   = blockIdx.x / 125;
    const int n0q  = qt * 64;
    const int lane = t & 63;
    const int w    = t >> 6;
    const int l15  = lane & 15;
    const int quad = lane >> 4;

    const int base = 125 / nsplit, rem = 125 - base * nsplit;
    const int kt0  = sp * base + (sp < rem ? sp : rem);
    const int cnt  = base + (sp < rem ? 1 : 0);

    // Q B-frags (k-dim 16 padded to 32 with zeros in quads 2,3)
    bf16x8 aq[4];
#pragma unroll
    for (int qh = 0; qh < 4; ++qh) {
        for (int j = 0; j < 8; ++j) aq[qh][j] = (__bf16)0.0f;
        if (quad < 2)
            aq[qh] = *reinterpret_cast<const bf16x8*>(
                &q_bf[(n0q + qh * 16 + l15) * 16 + quad * 8]);
    }
    bf16x8 ones;
    for (int j = 0; j < 8; ++j) ones[j] = (__bf16)1.0f;

    f32x4 acc[2][4];
#pragma unroll
    for (int mi = 0; mi < 2; ++mi)
#pragma unroll
        for (int qh = 0; qh < 4; ++qh)
            for (int r = 0; r < 4; ++r) acc[mi][qh][r] = 0.f;
    f32x4 lacc;
    for (int r = 0; r < 4; ++r) lacc[r] = 0.f;

    // K A-frag pointer (quads 2,3 stay zero)
    const __bf16* kptr = k_bf + (size_t)(kt0 * 64 + w * 16 + l15) * 16 + quad * 8;
    bf16x8 ak;
    for (int j = 0; j < 8; ++j) ak[j] = (__bf16)0.0f;
    if (quad < 2) ak = *reinterpret_cast<const bf16x8*>(kptr);

    int curb = 0;
    for (int it = 0; it < cnt; ++it) {
        const int kt = kt0 + it;

        // ---- V fragment loads for THIS tile (1KB contiguous per wave-instr);
        //      waitcnt lands before PV's first MFMA -> hidden under S phase
        bf16x8 a0[2], a1[2];
#pragma unroll
        for (int ks = 0; ks < 2; ++ks) {
            a0[ks] = *reinterpret_cast<const bf16x8*>(
                &v_pk[(size_t)(((kt * 16 + (2 * w) * 2 + ks) * 4 + quad) * 16 + l15) * 8]);
            a1[ks] = *reinterpret_cast<const bf16x8*>(
                &v_pk[(size_t)(((kt * 16 + (2 * w + 1) * 2 + ks) * 4 + quad) * 16 + l15) * 8]);
        }

        // ---- S phase: wave w owns keys w*16..+15; D[m=key][n=query]
        union SH { short4 sh; __bf16 b[4]; };
#pragma unroll
        for (int qh = 0; qh < 4; ++qh) {
            f32x4 s;
            for (int r = 0; r < 4; ++r) s[r] = 0.f;
            s = MFMA(ak, aq[qh], s);
            SH u;
            u.b[0] = (__bf16)__expf(s[0]); u.b[1] = (__bf16)__expf(s[1]);
            u.b[2] = (__bf16)__expf(s[2]); u.b[3] = (__bf16)__expf(s[3]);
            // keys j = w*16 + quad*4 + r -> chunk ((qh*2+ks)*4+quadS)*16+l15
            *reinterpret_cast<short4*>(
                &p_lds[curb][(((qh * 2 + (w >> 1)) * 4 + (w & 1) * 2 + (quad >> 1)) * 16 + l15) * 8
                             + (quad & 1) * 4]) = u.sh;
        }

        // ---- prefetch next tile's K frag (first use = next iter's S)
        bf16x8 akN = ak;
        if (it + 1 < cnt && quad < 2)
            akN = *reinterpret_cast<const bf16x8*>(kptr + 1024);

        __syncthreads();   // single barrier per iter (P double-buffered)

        // ---- PV phase: wave w owns ch-tiles {2w, 2w+1}; P reads 1KB-contig
#pragma unroll
        for (int ks = 0; ks < 2; ++ks) {
            bf16x8 p[4];
#pragma unroll
            for (int qh = 0; qh < 4; ++qh)
                p[qh] = *reinterpret_cast<const bf16x8*>(
                    &p_lds[curb][(((qh * 2 + ks) * 4 + quad) * 16 + l15) * 8]);
#pragma unroll
            for (int qh = 0; qh < 4; ++qh) {
                acc[0][qh] = MFMA(a0[ks], p[qh], acc[0][qh]);
                acc[1][qh] = MFMA(a1[ks], p[qh], acc[1][qh]);
            }
            lacc = MFMA(ones, p[w], lacc);   // row-sum for queries w*16..+15
        }

        ak = akN; kptr += 1024;
        curb ^= 1;
    }

    // ---- epilogue: transpose av via LDS (XOR-swizzled), coalesced store
    __syncthreads();                     // all P reads done; reuse p_lds
    __bf16* av_l = &p_lds[0][0];         // 16 KB = 64q x 128c bf16
    union SH2 { short4 sh; __bf16 b[4]; };
#pragma unroll
    for (int mi = 0; mi < 2; ++mi)
#pragma unroll
        for (int qh = 0; qh < 4; ++qh) {
            SH2 o;
            o.b[0] = (__bf16)acc[mi][qh][0]; o.b[1] = (__bf16)acc[mi][qh][1];
            o.b[2] = (__bf16)acc[mi][qh][2]; o.b[3] = (__bf16)acc[mi][qh][3];
            int q    = qh * 16 + l15;
            int coct = (2 * w + mi) * 2 + (quad >> 1);
            int phys = q * 16 + (coct ^ (q & 7));
            *reinterpret_cast<short4*>(&av_l[phys * 8 + (quad & 1) * 4]) = o.sh;
        }
    __syncthreads();
    __bf16* dst = av_part + (size_t)sp * 1024000 + (size_t)n0q * 128;
#pragma unroll
    for (int r = 0; r < 4; ++r) {
        int g = r * 256 + t;
        int q = g >> 4, oc = g & 15;
        int4 d = *reinterpret_cast<const int4*>(&av_l[(q * 16 + (oc ^ (q & 7))) * 8]);
        *reinterpret_cast<int4*>(&dst[q * 128 + oc * 8]) = d;   // 1KB contig/wave
    }
    if (quad == 0)
        l_part[sp * N_POS + n0q + w * 16 + l15] = lacc[0];
}

// ---------------------------------------------------------------------------
// Kernel C: split-K reduce + normalize (fp32) fused with y = wa@av + ba (MFMA)
// + BN stats. grid 500 (n-tiles of 16). b_lds pad-17 (R6's write was 16-way
// conflicted).
// ---------------------------------------------------------------------------
__global__ __launch_bounds__(256) void proj_out_kernel(
    const __bf16* __restrict__ av_part, const float* __restrict__ l_part,
    const float* __restrict__ wa, const float* __restrict__ ba,
    float* __restrict__ y_ws, float* __restrict__ bn_sum, float* __restrict__ bn_sumsq,
    int nsplit)
{
    __shared__ __bf16 b_lds[4352];   // (16 oc * 17 + 15 + 1) chunks * 8 elems

    const int t    = threadIdx.x;
    const int n0   = blockIdx.x * 16;
    const int lane = t & 63;
    const int w    = t >> 6;
    const int l15  = lane & 15;
    const int quad = lane >> 4;

    // build normalized B tile: 256 c-octets, 1 per thread (1KB-contig reads)
    {
        int n = t >> 4, oc = t & 15;
        float l = 0.f;
        for (int s = 0; s < nsplit; ++s) l += l_part[s * N_POS + n0 + n];
        float sum[8];
#pragma unroll
        for (int i = 0; i < 8; ++i) sum[i] = 0.f;
        for (int s = 0; s < nsplit; ++s) {
            bf16x8 p = *reinterpret_cast<const bf16x8*>(
                &av_part[(size_t)s * 1024000 + (size_t)(n0 + n) * 128 + oc * 8]);
#pragma unroll
            for (int i = 0; i < 8; ++i) sum[i] += (float)p[i];
        }
        float inv = 1.f / l;
        union { int4 iv; __bf16 b[8]; } u;
#pragma unroll
        for (int i = 0; i < 8; ++i) u.b[i] = (__bf16)(sum[i] * inv);
        *reinterpret_cast<int4*>(&b_lds[(oc * 17 + n) * 8]) = u.iv;
    }

    // A-frags: wa rows for mtiles {2w, 2w+1}
    bf16x8 aw[2][4];
    f32x4  acc[2];
    for (int mi = 0; mi < 2; ++mi) {
        int mt = 2 * w + mi;
        const float* wrow = wa + (mt * 16 + l15) * 128;
        for (int ks = 0; ks < 4; ++ks) {
            float4 f0 = *reinterpret_cast<const float4*>(wrow + ks * 32 + quad * 8);
            float4 f1 = *reinterpret_cast<const float4*>(wrow + ks * 32 + quad * 8 + 4);
            bf16x8 a;
            a[0]=(__bf16)f0.x; a[1]=(__bf16)f0.y; a[2]=(__bf16)f0.z; a[3]=(__bf16)f0.w;
            a[4]=(__bf16)f1.x; a[5]=(__bf16)f1.y; a[6]=(__bf16)f1.z; a[7]=(__bf16)f1.w;
            aw[mi][ks] = a;
        }
    }
    acc[0][0] = ba[(2 * w) * 16 + quad * 4 + 0];
    acc[0][1] = ba[(2 * w) * 16 + quad * 4 + 1];
    acc[0][2] = ba[(2 * w) * 16 + quad * 4 + 2];
    acc[0][3] = ba[(2 * w) * 16 + quad * 4 + 3];
    acc[1][0] = ba[(2 * w + 1) * 16 + quad * 4 + 0];
    acc[1][1] = ba[(2 * w + 1) * 16 + quad * 4 + 1];
    acc[1][2] = ba[(2 * w + 1) * 16 + quad * 4 + 2];
    acc[1][3] = ba[(2 * w + 1) * 16 + quad * 4 + 3];
    __syncthreads();

    for (int ks = 0; ks < 4; ++ks) {
        bf16x8 b = *reinterpret_cast<const bf16x8*>(
            &b_lds[((ks * 4 + quad) * 17 + l15) * 8]);
        acc[0] = MFMA(aw[0][ks], b, acc[0]);
        acc[1] = MFMA(aw[1][ks], b, acc[1]);
    }

    // y writes [c][n] + BN partial stats (one atomic pair per channel/block)
    for (int mi = 0; mi < 2; ++mi) {
#pragma unroll
        for (int r = 0; r < 4; ++r) {
            int ch = (2 * w + mi) * 16 + quad * 4 + r;
            float v = acc[mi][r];
            y_ws[ch * N_POS + n0 + l15] = v;
            float s1 = v, s2 = v * v;
#pragma unroll
            for (int off = 8; off >= 1; off >>= 1) {
                s1 += __shfl_xor(s1, off, 64);
                s2 += __shfl_xor(s2, off, 64);
            }
            if (l15 == 0) {
                atomicAdd(&bn_sum[ch],   s1);
                atomicAdd(&bn_sumsq[ch], s2);
            }
        }
    }
}

// ---------------------------------------------------------------------------
// Kernel D: BatchNorm (training stats) + ReLU + residual. grid 1000, block 256.
// ---------------------------------------------------------------------------
__global__ __launch_bounds__(256) void bn_relu_kernel(
    const float* __restrict__ y_ws, const float* __restrict__ x,
    const float* __restrict__ bn_sum, const float* __restrict__ bn_sumsq,
    const float* __restrict__ bn_w, const float* __restrict__ bn_b,
    float* __restrict__ out)
{
    const int i4 = blockIdx.x * 256 + threadIdx.x;
    const int c  = i4 / 2000;
    const float mean  = bn_sum[c]   * (1.f / 8000.f);
    const float var   = bn_sumsq[c] * (1.f / 8000.f) - mean * mean;
    const float rstd  = rsqrtf(var + 1e-5f);
    const float scale = bn_w[c] * rstd;
    const float shift = bn_b[c] - mean * scale;

    float4 y4 = reinterpret_cast<const float4*>(y_ws)[i4];
    float4 x4 = reinterpret_cast<const float4*>(x)[i4];
    float4 o4;
    o4.x = fmaxf(y4.x * scale + shift, 0.f) + x4.x;
    o4.y = fmaxf(y4.y * scale + shift, 0.f) + x4.y;
    o4.z = fmaxf(y4.z * scale + shift, 0.f) + x4.z;
    o4.w = fmaxf(y4.w * scale + shift, 0.f) + x4.w;
    reinterpret_cast<float4*>(out)[i4] = o4;
}

// ---------------------------------------------------------------------------
extern "C" void kernel_launch(void* const* d_in, const int* in_sizes, int n_in,
                              void* d_out, int out_size, void* d_ws, size_t ws_size,
                              hipStream_t stream)
{
    const float* x    = (const float*)d_in[0];
    const float* wq   = (const float*)d_in[1];
    const float* bq   = (const float*)d_in[2];
    const float* wk   = (const float*)d_in[3];
    const float* bk   = (const float*)d_in[4];
    const float* wv   = (const float*)d_in[5];
    const float* bv   = (const float*)d_in[6];
    const float* wa   = (const float*)d_in[7];
    const float* ba   = (const float*)d_in[8];
    const float* bn_w = (const float*)d_in[9];
    const float* bn_b = (const float*)d_in[10];
    float* out = (float*)d_out;

    // nsplit=25 needs 58,657,024 B of ws; fall back to 10 (27,457,024 B) if short.
    const int nsplit = (ws_size >= 58657024ull) ? 25 : 10;

    char* base = (char*)d_ws;
    size_t avB = (size_t)nsplit * 2048000;             // bf16 [sp][8000][128]
    __bf16* av_part = (__bf16*)base;
    __bf16* q_bf    = (__bf16*)(base + avB);                       // 256,000 B
    __bf16* k_bf    = (__bf16*)(base + avB + 256000);              // 256,000 B
    __bf16* v_pk    = (__bf16*)(base + avB + 512000);              // 2,048,000 B
    float*  l_part  = (float*)(base + avB + 2560000);              // nsplit*32,000 B
    float*  bn_sum   = (float*)(base + avB + 2560000 + (size_t)nsplit * 32000);
    float*  bn_sumsq = bn_sum + 128;                               // 1,024 B total
    float*  y_ws    = (float*)(base + avB + 2560000 + (size_t)nsplit * 32000 + 1024);

    qkv_kernel<<<250, 256, 0, stream>>>(x, wq, bq, wk, bk, wv, bv,
                                        q_bf, k_bf, v_pk, bn_sum);
    attn_kernel<<<125 * nsplit, 256, 0, stream>>>(q_bf, k_bf, v_pk,
                                                  av_part, l_part, nsplit);
    proj_out_kernel<<<500, 256, 0, stream>>>(av_part, l_part, wa, ba,
                                             y_ws, bn_sum, bn_sumsq, nsplit);
    bn_relu_kernel<<<1000, 256, 0, stream>>>(y_ws, x, bn_sum, bn_sumsq,
                                             bn_w, bn_b, out);
}

// Round 9
// 178.328 us; speedup vs baseline: 2.1723x; 1.8931x over previous
//
#include <hip/hip_runtime.h>
#include <math.h>

#define N_POS 8000

typedef __bf16 bf16x8 __attribute__((ext_vector_type(8)));
typedef float  f32x4  __attribute__((ext_vector_type(4)));

#define MFMA(a,b,c) __builtin_amdgcn_mfma_f32_16x16x32_bf16((a),(b),(c),0,0,0)

// MFMA 16x16x32 lane layouts (verified m89/m120):
//   A[m][k]: m = lane&15, k = (lane>>4)*8 + j
//   B[k][n]: n = lane&15, k = (lane>>4)*8 + j
//   D[m][n]: n = lane&15, m = (lane>>4)*4 + reg

#define GLOAD_LDS(gp, lp) \
    __builtin_amdgcn_global_load_lds( \
        (const __attribute__((address_space(1))) void*)(gp), \
        (__attribute__((address_space(3))) void*)(lp), 16, 0, 0)

// ---------------------------------------------------------------------------
// Kernel A: QKV projections via MFMA. grid 250 (n-tiles of 32), block 256.
// BYTE-EXACT copy of the R5 kernel (verified: passed, 177us run).
// q_bf,k_bf: [n][16] bf16.  v_bf: [c][8000] bf16.
// ---------------------------------------------------------------------------
__global__ __launch_bounds__(256) void qkv_kernel(
    const float* __restrict__ x,
    const float* __restrict__ wq, const float* __restrict__ bq,
    const float* __restrict__ wk, const float* __restrict__ bk,
    const float* __restrict__ wv, const float* __restrict__ bv,
    __bf16* __restrict__ q_bf, __bf16* __restrict__ k_bf, __bf16* __restrict__ v_bf)
{
    __shared__ __bf16 x_lds[32 * 136];          // [n][c]
    __shared__ __bf16 v_out[128 * 36];          // [ch][n]

    const int t    = threadIdx.x;
    const int n0   = blockIdx.x * 32;
    const int lane = t & 63;
    const int w    = t >> 6;
    const int l15  = lane & 15;
    const int quad = lane >> 4;

    // stage x tile [128c x 32n] fp32 -> x_lds[n][c] bf16 (transpose+convert)
    for (int r = 0; r < 4; ++r) {
        int f = r * 256 + t;
        int ch = f >> 3, n4 = f & 7;
        float4 xv = *reinterpret_cast<const float4*>(&x[ch * N_POS + n0 + n4 * 4]);
        x_lds[(n4 * 4 + 0) * 136 + ch] = (__bf16)xv.x;
        x_lds[(n4 * 4 + 1) * 136 + ch] = (__bf16)xv.y;
        x_lds[(n4 * 4 + 2) * 136 + ch] = (__bf16)xv.z;
        x_lds[(n4 * 4 + 3) * 136 + ch] = (__bf16)xv.w;
    }

    // A-frags: weight rows fp32->bf16 in regs. wave w owns mtiles {w, w+4, w+8<10}
    bf16x8 aw[3][4];
    f32x4  acc[3][2];
    const int nmt = (w < 2) ? 3 : 2;
    for (int mi = 0; mi < nmt; ++mi) {
        int mt = w + 4 * mi;
        const float *wrow, *brow;
        if (mt == 0)      { wrow = wq + l15 * 128;               brow = bq; }
        else if (mt == 1) { wrow = wk + l15 * 128;               brow = bk; }
        else              { wrow = wv + ((mt - 2) * 16 + l15) * 128;
                            brow = bv + (mt - 2) * 16; }
        for (int ks = 0; ks < 4; ++ks) {
            float4 f0 = *reinterpret_cast<const float4*>(wrow + ks * 32 + quad * 8);
            float4 f1 = *reinterpret_cast<const float4*>(wrow + ks * 32 + quad * 8 + 4);
            bf16x8 a;
            a[0]=(__bf16)f0.x; a[1]=(__bf16)f0.y; a[2]=(__bf16)f0.z; a[3]=(__bf16)f0.w;
            a[4]=(__bf16)f1.x; a[5]=(__bf16)f1.y; a[6]=(__bf16)f1.z; a[7]=(__bf16)f1.w;
            aw[mi][ks] = a;
        }
        for (int ni = 0; ni < 2; ++ni) {
            acc[mi][ni][0] = brow[quad * 4 + 0]; acc[mi][ni][1] = brow[quad * 4 + 1];
            acc[mi][ni][2] = brow[quad * 4 + 2]; acc[mi][ni][3] = brow[quad * 4 + 3];
        }
    }
    __syncthreads();

    for (int ks = 0; ks < 4; ++ks) {
        bf16x8 b0 = *reinterpret_cast<const bf16x8*>(&x_lds[(0  + l15) * 136 + ks * 32 + quad * 8]);
        bf16x8 b1 = *reinterpret_cast<const bf16x8*>(&x_lds[(16 + l15) * 136 + ks * 32 + quad * 8]);
        for (int mi = 0; mi < nmt; ++mi) {
            acc[mi][0] = MFMA(aw[mi][ks], b0, acc[mi][0]);
            acc[mi][1] = MFMA(aw[mi][ks], b1, acc[mi][1]);
        }
    }

    union S4 { short4 s; __bf16 b[4]; };
    for (int mi = 0; mi < nmt; ++mi) {
        int mt = w + 4 * mi;
        for (int ni = 0; ni < 2; ++ni) {
            S4 u;
            u.b[0]=(__bf16)acc[mi][ni][0]; u.b[1]=(__bf16)acc[mi][ni][1];
            u.b[2]=(__bf16)acc[mi][ni][2]; u.b[3]=(__bf16)acc[mi][ni][3];
            int n = n0 + ni * 16 + l15;
            if (mt == 0) {
                *reinterpret_cast<short4*>(&q_bf[n * 16 + quad * 4]) = u.s;
            } else if (mt == 1) {
                *reinterpret_cast<short4*>(&k_bf[n * 16 + quad * 4]) = u.s;
            } else {
                int ch0 = (mt - 2) * 16 + quad * 4;
                int nl  = ni * 16 + l15;
                v_out[(ch0 + 0) * 36 + nl] = u.b[0];
                v_out[(ch0 + 1) * 36 + nl] = u.b[1];
                v_out[(ch0 + 2) * 36 + nl] = u.b[2];
                v_out[(ch0 + 3) * 36 + nl] = u.b[3];
            }
        }
    }
    __syncthreads();
    for (int r = 0; r < 4; ++r) {
        int f = r * 256 + t;
        int ch = f >> 3, n4 = f & 7;
        int2 d = *reinterpret_cast<const int2*>(&v_out[ch * 36 + n4 * 4]);
        *reinterpret_cast<int2*>(&v_bf[ch * N_POS + n0 + n4 * 4]) = d;
    }
}

// ---------------------------------------------------------------------------
// Kernel B: fused attention, split-K, MFMA, global_load_lds double-buffer.
// BYTE-EXACT R5 kernel (measured 60us, passed) with exactly two edits:
//   (1) R5's UB kt0 initializer replaced by the equivalent clean form;
//   (2) split count is a runtime arg (nsplit); grid = 250*nsplit.
// Everything else (staging maps, XOR swizzle, P layout, barriers) unchanged.
// ---------------------------------------------------------------------------
__global__ __launch_bounds__(256, 4) void attn_kernel(
    const __bf16* __restrict__ q_bf, const __bf16* __restrict__ k_bf,
    const __bf16* __restrict__ v_bf, float* __restrict__ av_part,
    float* __restrict__ l_part, int nsplit)
{
    __shared__ __bf16 v_buf[2][8192];   // 16 KB each
    __shared__ __bf16 k_buf[2][1024];   // 2 KB each
    __shared__ __bf16 p_lds[2048];      // 4 KB;  total = 40960 B -> 4 blocks/CU

    const int t    = threadIdx.x;
    const int qt   = blockIdx.x % 250;
    const int sp   = blockIdx.x / 250;
    const int n0q  = qt * 32;
    const int lane = t & 63;
    const int w    = t >> 6;
    const int l15  = lane & 15;
    const int quad = lane >> 4;

    // staging maps (per lane, loop-invariant)
    const int chL   = lane >> 3;              // V: low 3 bits of channel
    const int vpart = (lane & 7) ^ chL;       // V: key-octet (XOR swizzle)
    const int kkey  = lane >> 1;              // K: key within 32-key half
    const int khalf = lane & 1;               // K: dim half

    // Q B-frags in registers (k-dim 16 padded to 32 with zeros)
    bf16x8 aq[2];
    for (int ni = 0; ni < 2; ++ni) {
        for (int j = 0; j < 8; ++j) aq[ni][j] = (__bf16)0.0f;
        if (quad < 2)
            aq[ni] = *reinterpret_cast<const bf16x8*>(
                &q_bf[(n0q + ni * 16 + l15) * 16 + quad * 8]);
    }
    bf16x8 ones;
    for (int j = 0; j < 8; ++j) ones[j] = (__bf16)1.0f;

    f32x4 acc[2][2];
    for (int mi = 0; mi < 2; ++mi)
        for (int ni = 0; ni < 2; ++ni)
            for (int r = 0; r < 4; ++r) acc[mi][ni][r] = 0.f;
    f32x4 lacc[2];
    for (int ni = 0; ni < 2; ++ni)
        for (int r = 0; r < 4; ++r) lacc[ni][r] = 0.f;

    const int base = 125 / nsplit, rem = 125 - base * nsplit;
    const int kt0  = sp * base + (sp < rem ? sp : rem);
    const int cnt  = base + (sp < rem ? 1 : 0);

    // issue one tile's staging DMA: 4 V ops (wave-split) + 2 K ops
    auto stage = [&](int kt, int buf) {
        const int n0k = kt * 64;
        for (int r = 0; r < 4; ++r) {
            int R = w * 4 + r;   // wave-uniform LDS base
            GLOAD_LDS(v_bf + (8 * R + chL) * N_POS + n0k + vpart * 8,
                      &v_buf[buf][R * 512]);
        }
        for (int h = 0; h < 2; ++h) {
            GLOAD_LDS(k_bf + (size_t)(n0k + h * 32 + kkey) * 16 + khalf * 8,
                      &k_buf[buf][h * 512]);
        }
    };

    stage(kt0, 0);

    const int oS  = w * 2 + (quad >> 1);   // P-write octet
    const int sub = (quad & 1) * 4;        // P-write elem offset in chunk

    for (int it = 0; it < cnt; ++it) {
        const int kt  = kt0 + it;
        const int cur = it & 1;
        __syncthreads();   // barrier_A: cur DMA drained; prev PV reads done

        // ---- S phase: A = K rows (wave w -> keys w*16..+15), B = Q regs
        bf16x8 ak;
        for (int j = 0; j < 8; ++j) ak[j] = (__bf16)0.0f;
        if (quad < 2)
            ak = *reinterpret_cast<const bf16x8*>(
                &k_buf[cur][(w * 16 + l15) * 16 + quad * 8]);
        f32x4 s0, s1;
        for (int r = 0; r < 4; ++r) { s0[r] = 0.f; s1[r] = 0.f; }
        s0 = MFMA(ak, aq[0], s0);   // D[m=key][n=q]
        s1 = MFMA(ak, aq[1], s1);
        union SH { short4 sh; __bf16 b[4]; };
        {
            SH u;
            u.b[0] = (__bf16)__expf(s0[0]); u.b[1] = (__bf16)__expf(s0[1]);
            u.b[2] = (__bf16)__expf(s0[2]); u.b[3] = (__bf16)__expf(s0[3]);
            *reinterpret_cast<short4*>(&p_lds[(oS * 32 + l15) * 8 + sub]) = u.sh;
            u.b[0] = (__bf16)__expf(s1[0]); u.b[1] = (__bf16)__expf(s1[1]);
            u.b[2] = (__bf16)__expf(s1[2]); u.b[3] = (__bf16)__expf(s1[3]);
            *reinterpret_cast<short4*>(&p_lds[(oS * 32 + 16 + l15) * 8 + sub]) = u.sh;
        }
        __syncthreads();   // barrier_B: P visible; nothing outstanding -> cheap

        // ---- issue next tile's DMA (drains at next barrier_A, hidden under PV)
        if (it + 1 < cnt) stage(kt + 1, cur ^ 1);

        // ---- PV phase: wave w owns ch-tiles {2w, 2w+1}
        const int chl = l15 & 7;
        for (int ks = 0; ks < 2; ++ks) {
            int pz = ((ks * 4 + quad) ^ chl);
            bf16x8 a0 = *reinterpret_cast<const bf16x8*>(
                &v_buf[cur][(((2 * w)     * 2 + (l15 >> 3)) * 64 + chl * 8 + pz) * 8]);
            bf16x8 a1 = *reinterpret_cast<const bf16x8*>(
                &v_buf[cur][(((2 * w + 1) * 2 + (l15 >> 3)) * 64 + chl * 8 + pz) * 8]);
            bf16x8 p0 = *reinterpret_cast<const bf16x8*>(
                &p_lds[((ks * 4 + quad) * 32 + 0  + l15) * 8]);
            bf16x8 p1 = *reinterpret_cast<const bf16x8*>(
                &p_lds[((ks * 4 + quad) * 32 + 16 + l15) * 8]);
            acc[0][0] = MFMA(a0, p0, acc[0][0]);
            acc[0][1] = MFMA(a0, p1, acc[0][1]);
            acc[1][0] = MFMA(a1, p0, acc[1][0]);
            acc[1][1] = MFMA(a1, p1, acc[1][1]);
            if (w == 0) {
                lacc[0] = MFMA(ones, p0, lacc[0]);
                lacc[1] = MFMA(ones, p1, lacc[1]);
            }
        }
    }

    // write av partials: av_part[sp][n][c] fp32
    float* dst = av_part + (size_t)sp * 1024000;
    for (int mi = 0; mi < 2; ++mi)
        for (int ni = 0; ni < 2; ++ni) {
            int n  = n0q + ni * 16 + l15;
            int ch = (2 * w + mi) * 16 + quad * 4;
            *reinterpret_cast<f32x4*>(&dst[n * 128 + ch]) = acc[mi][ni];
        }
    if (w == 0 && quad == 0) {
        l_part[sp * N_POS + n0q + 0  + l15] = lacc[0][0];
        l_part[sp * N_POS + n0q + 16 + l15] = lacc[1][0];
    }
}

// ---------------------------------------------------------------------------
// Kernel C: split-K reduce + normalize (fp32, in LDS) fused with
// y = wa @ av + ba (MFMA) + BN stats.  BYTE-EXACT R5 kernel; only the split
// loop bound is now the runtime arg nsplit.  grid 250.
// ---------------------------------------------------------------------------
__global__ __launch_bounds__(256) void proj_out_kernel(
    const float* __restrict__ av_part, const float* __restrict__ l_part,
    const float* __restrict__ wa, const float* __restrict__ ba,
    float* __restrict__ y_ws, float* __restrict__ bn_sum, float* __restrict__ bn_sumsq,
    int nsplit)
{
    __shared__ __bf16 b_lds[4096];   // 32n x 128c fragment-packed, swizzled

    const int t    = threadIdx.x;
    const int n0   = blockIdx.x * 32;
    const int lane = t & 63;
    const int w    = t >> 6;
    const int l15  = lane & 15;
    const int quad = lane >> 4;

    // build normalized B tile: 512 c-octets, 2 per thread (coalesced reads)
    for (int r = 0; r < 2; ++r) {
        int g = r * 256 + t;
        int n = g >> 4, oc = g & 15;
        float l = 0.f;
        for (int s = 0; s < nsplit; ++s) l += l_part[s * N_POS + n0 + n];
        float4 a0 = make_float4(0.f, 0.f, 0.f, 0.f);
        float4 a1 = make_float4(0.f, 0.f, 0.f, 0.f);
        for (int s = 0; s < nsplit; ++s) {
            const float* p = av_part + (size_t)s * 1024000 + (n0 + n) * 128 + oc * 8;
            float4 u = *reinterpret_cast<const float4*>(p);
            float4 v = *reinterpret_cast<const float4*>(p + 4);
            a0.x += u.x; a0.y += u.y; a0.z += u.z; a0.w += u.w;
            a1.x += v.x; a1.y += v.y; a1.z += v.z; a1.w += v.w;
        }
        float inv = 1.f / l;
        union { int4 iv; __bf16 b[8]; } u;
        u.b[0]=(__bf16)(a0.x*inv); u.b[1]=(__bf16)(a0.y*inv);
        u.b[2]=(__bf16)(a0.z*inv); u.b[3]=(__bf16)(a0.w*inv);
        u.b[4]=(__bf16)(a1.x*inv); u.b[5]=(__bf16)(a1.y*inv);
        u.b[6]=(__bf16)(a1.z*inv); u.b[7]=(__bf16)(a1.w*inv);
        int A = (n >> 4) * 16 + oc;
        int slot = (n & 15) ^ (oc & 7);
        *reinterpret_cast<int4*>(&b_lds[(A * 16 + slot) * 8]) = u.iv;
    }

    // A-frags: wa rows for mtiles {2w, 2w+1}
    bf16x8 aw[2][4];
    f32x4  acc[2][2];
    for (int mi = 0; mi < 2; ++mi) {
        int mt = 2 * w + mi;
        const float* wrow = wa + (mt * 16 + l15) * 128;
        for (int ks = 0; ks < 4; ++ks) {
            float4 f0 = *reinterpret_cast<const float4*>(wrow + ks * 32 + quad * 8);
            float4 f1 = *reinterpret_cast<const float4*>(wrow + ks * 32 + quad * 8 + 4);
            bf16x8 a;
            a[0]=(__bf16)f0.x; a[1]=(__bf16)f0.y; a[2]=(__bf16)f0.z; a[3]=(__bf16)f0.w;
            a[4]=(__bf16)f1.x; a[5]=(__bf16)f1.y; a[6]=(__bf16)f1.z; a[7]=(__bf16)f1.w;
            aw[mi][ks] = a;
        }
        for (int ni = 0; ni < 2; ++ni) {
            acc[mi][ni][0] = ba[mt * 16 + quad * 4 + 0];
            acc[mi][ni][1] = ba[mt * 16 + quad * 4 + 1];
            acc[mi][ni][2] = ba[mt * 16 + quad * 4 + 2];
            acc[mi][ni][3] = ba[mt * 16 + quad * 4 + 3];
        }
    }
    __syncthreads();

    for (int ks = 0; ks < 4; ++ks) {
        int oc = ks * 4 + quad;
        int slot = l15 ^ (oc & 7);
        bf16x8 b0 = *reinterpret_cast<const bf16x8*>(&b_lds[((0  + oc) * 16 + slot) * 8]);
        bf16x8 b1 = *reinterpret_cast<const bf16x8*>(&b_lds[((16 + oc) * 16 + slot) * 8]);
        for (int mi = 0; mi < 2; ++mi) {
            acc[mi][0] = MFMA(aw[mi][ks], b0, acc[mi][0]);
            acc[mi][1] = MFMA(aw[mi][ks], b1, acc[mi][1]);
        }
    }

    // y writes [c][n] + BN partial stats
    for (int mi = 0; mi < 2; ++mi) {
        for (int r = 0; r < 4; ++r) {
            int ch = (2 * w + mi) * 16 + quad * 4 + r;
            float v0 = acc[mi][0][r];
            float v1 = acc[mi][1][r];
            y_ws[ch * N_POS + n0 + 0  + l15] = v0;
            y_ws[ch * N_POS + n0 + 16 + l15] = v1;
            float s1 = v0 + v1;
            float s2 = v0 * v0 + v1 * v1;
#pragma unroll
            for (int off = 8; off >= 1; off >>= 1) {
                s1 += __shfl_xor(s1, off, 64);
                s2 += __shfl_xor(s2, off, 64);
            }
            if (l15 == 0) {
                atomicAdd(&bn_sum[ch],   s1);
                atomicAdd(&bn_sumsq[ch], s2);
            }
        }
    }
}

// ---------------------------------------------------------------------------
// Kernel D: BatchNorm (training stats) + ReLU + residual. grid 1000, block 256.
// ---------------------------------------------------------------------------
__global__ __launch_bounds__(256) void bn_relu_kernel(
    const float* __restrict__ y_ws, const float* __restrict__ x,
    const float* __restrict__ bn_sum, const float* __restrict__ bn_sumsq,
    const float* __restrict__ bn_w, const float* __restrict__ bn_b,
    float* __restrict__ out)
{
    const int i4 = blockIdx.x * 256 + threadIdx.x;
    const int c  = i4 / 2000;
    const float mean  = bn_sum[c]   * (1.f / 8000.f);
    const float var   = bn_sumsq[c] * (1.f / 8000.f) - mean * mean;
    const float rstd  = rsqrtf(var + 1e-5f);
    const float scale = bn_w[c] * rstd;
    const float shift = bn_b[c] - mean * scale;

    float4 y4 = reinterpret_cast<const float4*>(y_ws)[i4];
    float4 x4 = reinterpret_cast<const float4*>(x)[i4];
    float4 o4;
    o4.x = fmaxf(y4.x * scale + shift, 0.f) + x4.x;
    o4.y = fmaxf(y4.y * scale + shift, 0.f) + x4.y;
    o4.z = fmaxf(y4.z * scale + shift, 0.f) + x4.z;
    o4.w = fmaxf(y4.w * scale + shift, 0.f) + x4.w;
    reinterpret_cast<float4*>(out)[i4] = o4;
}

// ---------------------------------------------------------------------------
extern "C" void kernel_launch(void* const* d_in, const int* in_sizes, int n_in,
                              void* d_out, int out_size, void* d_ws, size_t ws_size,
                              hipStream_t stream)
{
    const float* x    = (const float*)d_in[0];
    const float* wq   = (const float*)d_in[1];
    const float* bq   = (const float*)d_in[2];
    const float* wk   = (const float*)d_in[3];
    const float* bk   = (const float*)d_in[4];
    const float* wv   = (const float*)d_in[5];
    const float* bv   = (const float*)d_in[6];
    const float* wa   = (const float*)d_in[7];
    const float* ba   = (const float*)d_in[8];
    const float* bn_w = (const float*)d_in[9];
    const float* bn_b = (const float*)d_in[10];
    float* out = (float*)d_out;

    // nsplit=10 needs 47,937,024 B (evidence ws >= 58.66 MB from R7's
    // WRITE_SIZE=61.7MB => its nsplit-25 branch ran). Fallback = exact R5.
    const int nsplit = (ws_size >= 47937024ull) ? 10 : 5;

    char* base = (char*)d_ws;
    size_t avB = (size_t)nsplit * 4096000;             // fp32 [sp][8000][128]
    float*  av_part = (float*)base;
    __bf16* q_bf    = (__bf16*)(base + avB);                       //   256,000 B
    __bf16* k_bf    = (__bf16*)(base + avB + 256000);              //   256,000 B
    __bf16* v_bf    = (__bf16*)(base + avB + 512000);              // 2,048,000 B
    float*  l_part  = (float*)(base + avB + 2560000);              // nsplit*32,000 B
    float*  bn_sum   = (float*)(base + avB + 2560000 + (size_t)nsplit * 32000);
    float*  bn_sumsq = bn_sum + 128;                               // 1,024 B total
    float*  y_ws    = (float*)(base + avB + 2560000 + (size_t)nsplit * 32000 + 1024);

    hipMemsetAsync(bn_sum, 0, 1024, stream);
    qkv_kernel<<<250, 256, 0, stream>>>(x, wq, bq, wk, bk, wv, bv, q_bf, k_bf, v_bf);
    attn_kernel<<<250 * nsplit, 256, 0, stream>>>(q_bf, k_bf, v_bf,
                                                  av_part, l_part, nsplit);
    proj_out_kernel<<<250, 256, 0, stream>>>(av_part, l_part, wa, ba,
                                             y_ws, bn_sum, bn_sumsq, nsplit);
    bn_relu_kernel<<<1000, 256, 0, stream>>>(y_ws, x, bn_sum, bn_sumsq,
                                             bn_w, bn_b, out);
}